// Round 9
// baseline (269.779 us; speedup 1.0000x reference)
//
#include <hip/hip_runtime.h>
#include <hip/hip_bf16.h>
#include <math.h>

#define BATCH 64
#define TT 512
#define HH 1024
#define KK 8
#define ROWS (BATCH * TT)          // 32768
#define SEG  (ROWS * KK)           // 262144 floats per logits output
#define TAGS_OFF (3 * SEG)         // 786432
#define LOSS_OFF (TAGS_OFF + BATCH * 3 * TT)  // 884736
#define PART_STRIDE (ROWS * 24)    // 786432 floats per K-split partial
#define LOSS_WS_OFF 3407872        // floats (13 MB) — after 4x partials (12 MB)

// ---------------------------------------------------------------------------
// Kernel 1a: fused 3-head GEMM, split-K=4. 512 blocks x 64 threads (1 wave).
// Block (rg, kq): rows [rg*256, +256), K [kq*256, +256). Lane owns 4 rows
// (4l..4l+3): per stage 1 ds_read_b128 x + 6 ds_read_b128 weight broadcast
// + 96 FMAs -> weight-DS per FMA is 4x lower than R7 (the confirmed bind).
// x tile transposed [16 h][256 r] so compute reads are b128 conflict-free.
// Partials to ws (deterministic); reduce kernel sums + bias.
// ---------------------------------------------------------------------------
#define FMA8B(base, wA, wB, xe)                               \
    acc[(base) + 0] = fmaf(xe, wA.x, acc[(base) + 0]);        \
    acc[(base) + 1] = fmaf(xe, wA.y, acc[(base) + 1]);        \
    acc[(base) + 2] = fmaf(xe, wA.z, acc[(base) + 2]);        \
    acc[(base) + 3] = fmaf(xe, wA.w, acc[(base) + 3]);        \
    acc[(base) + 4] = fmaf(xe, wB.x, acc[(base) + 4]);        \
    acc[(base) + 5] = fmaf(xe, wB.y, acc[(base) + 5]);        \
    acc[(base) + 6] = fmaf(xe, wB.z, acc[(base) + 6]);        \
    acc[(base) + 7] = fmaf(xe, wB.w, acc[(base) + 7]);

__global__ __launch_bounds__(64) void gemm_heads(
    const float* __restrict__ enc,
    const float* __restrict__ Wt,
    const float* __restrict__ Wp,
    const float* __restrict__ Wm,
    float* __restrict__ part)
{
    __shared__ float xt[2][16][256];     // 32 KB, transposed x tiles
    __shared__ float wl[2][16][24];      // 3 KB, weight tiles

    int lane = threadIdx.x;
    int rg = blockIdx.x >> 2;
    int kq = blockIdx.x & 3;
    int r0 = rg * 256;
    int h0 = kq * 256;

    const float* encb = enc + (size_t)r0 * HH + h0;
    const float* Wqt = Wt + h0 * 8;
    const float* Wqp = Wp + h0 * 8;
    const float* Wqm = Wm + h0 * 8;

    int srow = lane >> 2;                // staging: row-in-16-group
    int schunk = lane & 3;               // staging: h-chunk (4 floats)
    int wrow = lane >> 3;
    int wcol = lane & 7;

    float acc[96];
#pragma unroll
    for (int c = 0; c < 96; ++c) acc[c] = 0.f;

    float4 sreg[16];
    float  wreg[6];

#define LOADT(it)                                                             \
    {                                                                         \
        _Pragma("unroll")                                                     \
        for (int j = 0; j < 16; ++j)                                          \
            sreg[j] = *(const float4*)(encb + (size_t)(16 * j + srow) * HH +  \
                                       (it) * 16 + 4 * schunk);               \
    }
// scatter into transposed tile: sreg[j].e -> xt[4*schunk+e][16*j+srow]
#define WRITET(buf)                                                           \
    {                                                                         \
        _Pragma("unroll")                                                     \
        for (int j = 0; j < 16; ++j) {                                        \
            xt[buf][4 * schunk + 0][16 * j + srow] = sreg[j].x;               \
            xt[buf][4 * schunk + 1][16 * j + srow] = sreg[j].y;               \
            xt[buf][4 * schunk + 2][16 * j + srow] = sreg[j].z;               \
            xt[buf][4 * schunk + 3][16 * j + srow] = sreg[j].w;               \
        }                                                                     \
    }
#define WLOADG(it)                                                            \
    {                                                                         \
        const float* pt_ = Wqt + (it) * 128;                                  \
        const float* pp_ = Wqp + (it) * 128;                                  \
        const float* pm_ = Wqm + (it) * 128;                                  \
        wreg[0] = pt_[lane]; wreg[1] = pt_[64 + lane];                        \
        wreg[2] = pp_[lane]; wreg[3] = pp_[64 + lane];                        \
        wreg[4] = pm_[lane]; wreg[5] = pm_[64 + lane];                        \
    }
#define WWRITE(buf)                                                           \
    {                                                                         \
        wl[buf][wrow][wcol]          = wreg[0];                               \
        wl[buf][8 + wrow][wcol]      = wreg[1];                               \
        wl[buf][wrow][8 + wcol]      = wreg[2];                               \
        wl[buf][8 + wrow][8 + wcol]  = wreg[3];                               \
        wl[buf][wrow][16 + wcol]     = wreg[4];                               \
        wl[buf][8 + wrow][16 + wcol] = wreg[5];                               \
    }

    LOADT(0)
    WLOADG(0)
    WRITET(0)
    WWRITE(0)

    for (int it = 0; it < 16; ++it) {
        int cb = it & 1;
        if (it < 15) {                    // issue next tile's global loads early
            LOADT(it + 1)
            WLOADG(it + 1)
        }
#pragma unroll
        for (int hh = 0; hh < 16; ++hh) {
            const float4* wp_ = (const float4*)&wl[cb][hh][0];  // uniform -> bcast
            float4 W0 = wp_[0], W1 = wp_[1], W2 = wp_[2];
            float4 W3 = wp_[3], W4 = wp_[4], W5 = wp_[5];
            float4 xv = *(const float4*)&xt[cb][hh][4 * lane];  // rows 4l..4l+3
            FMA8B(0,  W0, W1, xv.x) FMA8B(8,  W2, W3, xv.x) FMA8B(16, W4, W5, xv.x)
            FMA8B(24, W0, W1, xv.y) FMA8B(32, W2, W3, xv.y) FMA8B(40, W4, W5, xv.y)
            FMA8B(48, W0, W1, xv.z) FMA8B(56, W2, W3, xv.z) FMA8B(64, W4, W5, xv.z)
            FMA8B(72, W0, W1, xv.w) FMA8B(80, W2, W3, xv.w) FMA8B(88, W4, W5, xv.w)
        }
        if (it < 15) {                    // write-late; single wave, no barrier
            WRITET(cb ^ 1)
            WWRITE(cb ^ 1)
        }
    }
#undef LOADT
#undef WRITET
#undef WLOADG
#undef WWRITE

    // partials: rows r0+4l..r0+4l+3, 24 cols each, c-major [row][24]
    float* pb = part + (size_t)kq * PART_STRIDE + (size_t)(r0 + 4 * lane) * 24;
#pragma unroll
    for (int j = 0; j < 4; ++j) {
        float* pr = pb + j * 24;
#pragma unroll
        for (int q = 0; q < 6; ++q)
            *(float4*)(pr + 4 * q) = make_float4(acc[j * 24 + 4 * q + 0],
                                                 acc[j * 24 + 4 * q + 1],
                                                 acc[j * 24 + 4 * q + 2],
                                                 acc[j * 24 + 4 * q + 3]);
    }
}

// ---------------------------------------------------------------------------
// Kernel 1b: sum 4 K-split partials + bias -> logits. 3072 blocks x 256.
// ---------------------------------------------------------------------------
__global__ __launch_bounds__(256) void gemm_reduce(
    const float* __restrict__ part,
    const float* __restrict__ bt, const float* __restrict__ bpv,
    const float* __restrict__ bm, float* __restrict__ out)
{
    int idx = blockIdx.x * 256 + threadIdx.x;          // < 786432
    int seg = idx >> 18;
    int row = (idx & 262143) >> 3;
    int col = idx & 7;
    size_t base = (size_t)row * 24 + seg * 8 + col;
    float s = part[base]
            + part[base + PART_STRIDE]
            + part[base + 2 * (size_t)PART_STRIDE]
            + part[base + 3 * (size_t)PART_STRIDE];
    const float* bb = (seg == 0) ? bt : (seg == 1) ? bpv : bm;
    out[idx] = s + bb[col];
}

// ---------------------------------------------------------------------------
// Pure-VALU cross-lane helpers
// ---------------------------------------------------------------------------
#define DPPF(x, ctrl) __int_as_float(__builtin_amdgcn_update_dpp(              \
    0, __float_as_int(x), ctrl, 0xF, 0xF, true))
#define SWIZF(x, pat) __int_as_float(__builtin_amdgcn_ds_swizzle(              \
    __float_as_int(x), pat))
#define BPERMF(a, x)  __int_as_float(__builtin_amdgcn_ds_bpermute(             \
    a, __float_as_int(x)))

__device__ __forceinline__ float rfl(float x) {
    return __int_as_float(__builtin_amdgcn_readfirstlane(__float_as_int(x)));
}

#if __has_builtin(__builtin_amdgcn_permlane16_swap)
__device__ __forceinline__ float xor16f(float x, int lane) {
    typedef unsigned uv2 __attribute__((ext_vector_type(2)));
    uv2 r = __builtin_amdgcn_permlane16_swap(__float_as_uint(x), __float_as_uint(x), false, false);
    return __uint_as_float((lane & 16) ? r.x : r.y);
}
#else
__device__ __forceinline__ float xor16f(float x, int lane) { return SWIZF(x, 0x401F); }
#endif

#if __has_builtin(__builtin_amdgcn_permlane32_swap)
__device__ __forceinline__ float xor32f(float x, int lane) {
    typedef unsigned uv2 __attribute__((ext_vector_type(2)));
    uv2 r = __builtin_amdgcn_permlane32_swap(__float_as_uint(x), __float_as_uint(x), false, false);
    return __uint_as_float((lane & 32) ? r.x : r.y);
}
#else
__device__ __forceinline__ float xor32f(float x, int lane) {
    return BPERMF(((lane ^ 32) << 2), x);
}
#endif

// ---------------------------------------------------------------------------
// Kernel 2: 192 blocks x 128 threads (2 waves). Wave 0: Viterbi (bit-exact,
// ballot argmax, chunked backtrack). Wave 1: CRF logZ in multiplicative form
// (no exp/log on the recurrence chain) + scores. (R5-R8 version, proven.)
// ---------------------------------------------------------------------------
__global__ __launch_bounds__(128) void crf_vit(
    const float* __restrict__ logits,
    const int* __restrict__ labels,
    const int* __restrict__ lens,
    const float* __restrict__ trans_t,
    const float* __restrict__ trans_p,
    const float* __restrict__ trans_m,
    float* __restrict__ out_tags,
    float* __restrict__ partial)
{
    __shared__ float llds[TT * KK];        // 16 KB
    __shared__ unsigned bpw[TT * 2];       // 4 KB backpointers (wave-0 private)
    __shared__ unsigned fmapw[64][2];
    __shared__ unsigned char bnd[64];

    int blk = blockIdx.x;
    int h   = blk >> 6;
    int b   = blk & 63;
    int tid = threadIdx.x;
    int wid = __builtin_amdgcn_readfirstlane(tid >> 6);
    int lane = tid & 63;
    int hi = lane >> 3, lo = lane & 7;
    unsigned char* bpb = (unsigned char*)bpw;

    const float* L = logits + ((size_t)h * BATCH + b) * (TT * KK);
    const float4* Lv = (const float4*)L;
    float4* lv = (float4*)llds;
#pragma unroll
    for (int i = 0; i < 8; ++i) lv[tid + 128 * i] = Lv[tid + 128 * i];
    __syncthreads();

    const float* TR = (h == 0) ? trans_t : (h == 1) ? trans_p : trans_m;
    int len = lens[b];
    float trA = TR[lo * 8 + hi];   // even step: kp=lo -> kn=hi
    float trB = TR[hi * 8 + lo];   // odd step:  kp=hi -> kn=lo

    if (wid == 0) {
        // ================= Viterbi wave (bit-exact) =================
        float av = llds[lo];

#define VIT_EVEN(t, LT)                                                        \
    {                                                                          \
        float v0 = av + trA;                                                   \
        float ra = fmaxf(v0, DPPF(v0, 0xB1));                                  \
        float rb = fmaxf(ra, DPPF(ra, 0x4E));                                  \
        float vmax = fmaxf(rb, DPPF(rb, 0x141));                               \
        unsigned long long mk = __ballot(v0 == vmax);                          \
        int vi = __builtin_ctz(((unsigned)(mk >> (lane & 56))) & 0xffu);       \
        if (lo == 0) bpb[(t) * 8 + hi] = (unsigned char)vi;                    \
        av = vmax + (LT);                                                      \
    }
#define VIT_ODD(t, LT)                                                         \
    {                                                                          \
        float v0 = av + trB;                                                   \
        float ra = fmaxf(v0, DPPF(v0, 0x128));                                 \
        float rb = fmaxf(ra, xor16f(ra, lane));                                \
        float vmax = fmaxf(rb, xor32f(rb, lane));                              \
        unsigned long long mk = __ballot(v0 == vmax);                          \
        unsigned long long sel = (mk >> lo) & 0x0101010101010101ULL;           \
        int vi = __builtin_ctzll(sel) >> 3;                                    \
        if (hi == 0) bpb[(t) * 8 + lo] = (unsigned char)vi;                    \
        av = vmax + (LT);                                                      \
    }

        float ltA = llds[8 + hi];
        float ltB = llds[16 + lo];
        for (int t = 1; t <= 509; t += 2) {
            float ltA2 = llds[(t + 2) * 8 + hi];
            int tb = (t + 3 <= 511) ? (t + 3) : 511;
            float ltB2 = llds[tb * 8 + lo];
            VIT_EVEN(t, ltA);
            VIT_ODD(t + 1, ltB);
            ltA = ltA2; ltB = ltB2;
        }
        VIT_EVEN(511, ltA);
#undef VIT_EVEN
#undef VIT_ODD

        float ra = fmaxf(av, DPPF(av, 0x128));
        float rb = fmaxf(ra, xor16f(ra, lane));
        float vmax = fmaxf(rb, xor32f(rb, lane));
        unsigned long long mk = __ballot(av == vmax);
        int last_ = __builtin_ctzll(mk) >> 3;

        asm volatile("" ::: "memory");

        // Phase A: lane l composes bp maps for t in [8l+1, 8l+8]
        int t0 = lane * 8;
        unsigned rw[16];
#pragma unroll
        for (int j = 0; j < 8; ++j) {
            int t = t0 + 1 + j;
            if (t <= 511) { rw[2 * j] = bpw[t * 2]; rw[2 * j + 1] = bpw[t * 2 + 1]; }
            else          { rw[2 * j] = 0x03020100u; rw[2 * j + 1] = 0x07060504u; }
        }
        unsigned sv[8];
#pragma unroll
        for (int i = 0; i < 8; ++i) sv[i] = i;
#pragma unroll
        for (int j = 7; j >= 0; --j) {
            unsigned d0 = rw[2 * j], d1 = rw[2 * j + 1];
#pragma unroll
            for (int i = 0; i < 8; ++i) {
                unsigned s = sv[i];
                unsigned d = (s < 4) ? d0 : d1;
                sv[i] = (d >> (8 * (s & 3))) & 0xffu;
            }
        }
        fmapw[lane][0] = sv[0] | (sv[1] << 8) | (sv[2] << 16) | (sv[3] << 24);
        fmapw[lane][1] = sv[4] | (sv[5] << 8) | (sv[6] << 16) | (sv[7] << 24);
        asm volatile("" ::: "memory");

        if (lane == 0) {
            unsigned cur = (unsigned)last_;
            for (int l = 63; l >= 0; --l) {
                unsigned d = (cur < 4) ? fmapw[l][0] : fmapw[l][1];
                cur = (d >> (8 * (cur & 3))) & 0xffu;
                bnd[l] = (unsigned char)cur;
            }
        }
        asm volatile("" ::: "memory");

        int off = h * 8;
        float* otag = out_tags + b * (3 * TT) + h * TT;
        unsigned curr = (lane == 63) ? (unsigned)last_ : (unsigned)bnd[lane + 1];
#pragma unroll
        for (int j = 7; j >= 0; --j) {
            unsigned d = (curr < 4) ? rw[2 * j] : rw[2 * j + 1];
            curr = (d >> (8 * (curr & 3))) & 0xffu;
            otag[t0 + j] = (float)((int)curr + off);
        }
    } else {
        // ============ CRF wave: multiplicative logsumexp ============
        float EA = __expf(trA);
        float EB = __expf(trB);
        float al0 = llds[lo];
        float c0 = rfl(al0);
        float S = __expf(al0 - c0);
        float Mc = c0;
        float r2 = 0.f, r3 = 0.f;
        const float LN8 = 2.0794415416798357f;

#define LSE_EVEN(t, LT)                                                        \
    {                                                                          \
        float c = rfl(LT) + LN8;                                               \
        float F = __expf((LT) - c);                                            \
        float P = S * EA;                                                      \
        float sa = P + DPPF(P, 0xB1);                                          \
        float sb = sa + DPPF(sa, 0x4E);                                        \
        float ss = sb + DPPF(sb, 0x141);                                       \
        if ((t) < len) { S = ss * F; Mc += c; }                                \
        r2 = r3; r3 = __logf(rfl(S));                                          \
    }
#define LSE_ODD(t, LT)                                                         \
    {                                                                          \
        float c = rfl(LT) + LN8;                                               \
        float F = __expf((LT) - c);                                            \
        float P = S * EB;                                                      \
        float sa = P + DPPF(P, 0x128);                                         \
        float sb = sa + xor16f(sa, lane);                                      \
        float ss = sb + xor32f(sb, lane);                                      \
        if ((t) < len) { S = ss * F; Mc += c; }                                \
        r2 = r3; r3 = __logf(rfl(S));                                          \
    }

        float ltA = llds[8 + hi];
        float ltB = llds[16 + lo];
        for (int t = 1; t <= 509; t += 2) {
            if ((t & 3) == 1) {
                float g = r2;
                S *= __expf(-g);
                Mc += g;
            }
            float ltA2 = llds[(t + 2) * 8 + hi];
            int tb = (t + 3 <= 511) ? (t + 3) : 511;
            float ltB2 = llds[tb * 8 + lo];
            LSE_EVEN(t, ltA);
            LSE_ODD(t + 1, ltB);
            ltA = ltA2; ltB = ltB2;
        }
        LSE_EVEN(511, ltA);
#undef LSE_EVEN
#undef LSE_ODD

        float aj = Mc + __logf(S);
        float za = fmaxf(aj, DPPF(aj, 0x128));
        float zb = fmaxf(za, xor16f(za, lane));
        float zmax = fmaxf(zb, xor32f(zb, lane));
        float ze = __expf(aj - zmax);
        float zs = ze + DPPF(ze, 0x128);
        float zs2 = zs + xor16f(zs, lane);
        float zsum = zs2 + xor32f(zs2, lane);
        float logZ = zmax + __logf(zsum);

        const int* lab = labels + b * (3 * TT) + h * TT;
        int off = h * 8;
        float sc = 0.f;
#pragma unroll
        for (int j = 0; j < 8; ++j) {
            int t = lane + 64 * j;
            if (t < len) {
                int tg = lab[t] - off;
                sc += llds[t * 8 + tg];
                if (t >= 1) {
                    int tp = lab[t - 1] - off;
                    sc += TR[tp * 8 + tg];
                }
            }
        }
#pragma unroll
        for (int d = 1; d <= 32; d <<= 1) sc += __shfl_xor(sc, d);

        if (lane == 0) partial[blk] = logZ - sc;
    }
}

// ---------------------------------------------------------------------------
// Kernel 3: deterministic loss reduction (192 partials -> scalar)
// ---------------------------------------------------------------------------
__global__ __launch_bounds__(64) void loss_reduce(
    const float* __restrict__ partial, float* __restrict__ out_loss)
{
    int lane = threadIdx.x;
    float s = partial[lane] + partial[lane + 64] + partial[lane + 128];
#pragma unroll
    for (int d = 1; d <= 32; d <<= 1) s += __shfl_xor(s, d);
    if (lane == 0) *out_loss = s;
}

// ---------------------------------------------------------------------------
extern "C" void kernel_launch(void* const* d_in, const int* in_sizes, int n_in,
                              void* d_out, int out_size, void* d_ws, size_t ws_size,
                              hipStream_t stream) {
    const float* enc    = (const float*)d_in[0];
    const int*   labels = (const int*)d_in[1];
    const int*   lens   = (const int*)d_in[2];
    const float* Wt     = (const float*)d_in[3];
    const float* bt     = (const float*)d_in[4];
    const float* Wp     = (const float*)d_in[5];
    const float* bpv    = (const float*)d_in[6];
    const float* Wm     = (const float*)d_in[7];
    const float* bm     = (const float*)d_in[8];
    const float* tr_t   = (const float*)d_in[9];
    const float* tr_p   = (const float*)d_in[10];
    const float* tr_m   = (const float*)d_in[11];

    float* out = (float*)d_out;
    float* gpart = (float*)d_ws;                       // 4 x 786432 floats (12 MB)
    float* lpart = (float*)d_ws + LOSS_WS_OFF;         // 192 floats @ 13 MB

    gemm_heads<<<512, 64, 0, stream>>>(enc, Wt, Wp, Wm, gpart);
    gemm_reduce<<<3072, 256, 0, stream>>>(gpart, bt, bpv, bm, out);
    crf_vit<<<192, 128, 0, stream>>>(out, labels, lens, tr_t, tr_p, tr_m,
                                     out + TAGS_OFF, lpart);
    loss_reduce<<<1, 64, 0, stream>>>(lpart, out + LOSS_OFF);
}

// Round 10
// 88.092 us; speedup vs baseline: 3.0625x; 3.0625x over previous
//
#include <hip/hip_runtime.h>
#include <hip/hip_bf16.h>
#include <math.h>

#define BATCH 64
#define TT 512
#define HH 1024
#define KK 8
#define ROWS (BATCH * TT)          // 32768
#define SEG  (ROWS * KK)           // 262144 floats per logits output
#define TAGS_OFF (3 * SEG)         // 786432
#define LOSS_OFF (TAGS_OFF + BATCH * 3 * TT)  // 884736

// ---------------------------------------------------------------------------
// Kernel 1: fused 3-head GEMM. 256 blocks x 256 thr (4 waves), block = 128
// rows, wave (kh,rh) = K-half x row-half, per-wave PRIVATE double-buffered
// tiles (no main-loop barriers, R7-proven). Lane = (r16, q4): 4 rows x 6
// outputs, acc[24]. Per hh: 1 ds_read_b128 x + b128+b64 weights (4 distinct
// q-addresses, hh-XOR-swizzled) + 24 FMA -> weight-DS per FMA is 12x lower
// than R7's uniform 6xb128. kh-halves reduced in-block via LDS overlay;
// coalesced bias-fused store (no separate reduce kernel).
// ---------------------------------------------------------------------------
__global__ __launch_bounds__(256) void gemm_heads(
    const float* __restrict__ enc,
    const float* __restrict__ Wt, const float* __restrict__ bt,
    const float* __restrict__ Wp, const float* __restrict__ bpv,
    const float* __restrict__ Wm, const float* __restrict__ bm,
    float* __restrict__ out)
{
    __shared__ float xt[4][2][16][68];    // 34.8 KB per-wave x tiles (padded)
    __shared__ float wl[4][2][16][32];    // 16.4 KB per-wave weight tiles
    __shared__ float biasl[24];

    int tid  = threadIdx.x;
    int lane = tid & 63;
    int w    = __builtin_amdgcn_readfirstlane(tid >> 6);
    int kh   = w >> 1;
    int rh   = w & 1;
    int r    = lane >> 2;        // row group 0..15 (rows 4r..4r+3)
    int q    = lane & 3;         // output group 0..3 (outputs 6q..6q+5)
    int rowblk = blockIdx.x * 128;

    if (tid < 24) {
        int hd = tid >> 3, cl = tid & 7;
        biasl[tid] = (hd == 0) ? bt[cl] : (hd == 1) ? bpv[cl] : bm[cl];
    }

    const float* encw = enc + (size_t)(rowblk + rh * 64) * HH + kh * 512;
    const float* Wkt = Wt + kh * 4096;
    const float* Wkp = Wp + kh * 4096;
    const float* Wkm = Wm + kh * 4096;

    int srow = lane >> 2;        // staging row base (adds 16*i)
    int schunk = lane & 3;       // staging h-chunk

    float acc[24];
#pragma unroll
    for (int c = 0; c < 24; ++c) acc[c] = 0.f;

    float4 sreg[4];
    float  wreg[6];

#define LOADT(it)                                                             \
    {                                                                         \
        _Pragma("unroll")                                                     \
        for (int i = 0; i < 4; ++i)                                           \
            sreg[i] = *(const float4*)(encw + (size_t)(srow + 16 * i) * HH +  \
                                       (it) * 16 + schunk * 4);               \
    }
#define WRITET(buf)                                                           \
    {                                                                         \
        _Pragma("unroll")                                                     \
        for (int i = 0; i < 4; ++i) {                                         \
            xt[w][buf][schunk * 4 + 0][srow + 16 * i] = sreg[i].x;            \
            xt[w][buf][schunk * 4 + 1][srow + 16 * i] = sreg[i].y;            \
            xt[w][buf][schunk * 4 + 2][srow + 16 * i] = sreg[i].z;            \
            xt[w][buf][schunk * 4 + 3][srow + 16 * i] = sreg[i].w;            \
        }                                                                     \
    }
#define WLOADG(it)                                                            \
    {                                                                         \
        wreg[0] = Wkt[(it) * 128 + lane]; wreg[1] = Wkt[(it) * 128 + 64 + lane]; \
        wreg[2] = Wkp[(it) * 128 + lane]; wreg[3] = Wkp[(it) * 128 + 64 + lane]; \
        wreg[4] = Wkm[(it) * 128 + lane]; wreg[5] = Wkm[(it) * 128 + 64 + lane]; \
    }
// float i of WLOADG = W[head=i>>1][h = (lane>>3)+8*(i&1)][col = lane&7]
// -> output c = 8*(i>>1)+col, q' = c/6, slot = c%6, store at hh-XOR-swizzled q
#define WWRITE(buf)                                                           \
    {                                                                         \
        int col_ = lane & 7;                                                  \
        _Pragma("unroll")                                                     \
        for (int i = 0; i < 6; ++i) {                                         \
            int hh_ = (lane >> 3) + 8 * (i & 1);                              \
            int c_  = 8 * (i >> 1) + col_;                                    \
            int q_  = (c_ * 43) >> 8;      /* c/6 for c<24 */                 \
            int s_  = c_ - 6 * q_;                                            \
            wl[w][buf][hh_][8 * (q_ ^ (hh_ & 3)) + s_] = wreg[i];             \
        }                                                                     \
    }

    LOADT(0)
    WLOADG(0)
    WRITET(0)
    WWRITE(0)

    for (int it = 0; it < 32; ++it) {
        int cb = it & 1;
        if (it < 31) {                      // issue next tile's loads early
            LOADT(it + 1)
            WLOADG(it + 1)
        }
#pragma unroll
        for (int hh = 0; hh < 16; ++hh) {
            float4 xv = *(const float4*)&xt[w][cb][hh][4 * r];
            const float* wp_ = &wl[w][cb][hh][8 * (q ^ (hh & 3))];
            float4 w0 = *(const float4*)wp_;          // weights 6q..6q+3
            float2 w1 = *(const float2*)(wp_ + 4);    // weights 6q+4..6q+5
#pragma unroll
            for (int j = 0; j < 4; ++j) {
                float xe = (j == 0) ? xv.x : (j == 1) ? xv.y : (j == 2) ? xv.z : xv.w;
                acc[j * 6 + 0] = fmaf(xe, w0.x, acc[j * 6 + 0]);
                acc[j * 6 + 1] = fmaf(xe, w0.y, acc[j * 6 + 1]);
                acc[j * 6 + 2] = fmaf(xe, w0.z, acc[j * 6 + 2]);
                acc[j * 6 + 3] = fmaf(xe, w0.w, acc[j * 6 + 3]);
                acc[j * 6 + 4] = fmaf(xe, w1.x, acc[j * 6 + 4]);
                acc[j * 6 + 5] = fmaf(xe, w1.y, acc[j * 6 + 5]);
            }
        }
        if (it < 31) {                      // write-late; per-wave private
            WRITET(cb ^ 1)
            WWRITE(cb ^ 1)
        }
    }
#undef LOADT
#undef WRITET
#undef WLOADG
#undef WWRITE

    // ---- kh reduce + coalesced store via LDS overlay fin[128][25] on xt ----
    __syncthreads();
    float* xf = &xt[0][0][0][0];
    int myrow = rh * 64 + 4 * r;
    if (kh == 1) {
#pragma unroll
        for (int j = 0; j < 4; ++j)
#pragma unroll
            for (int s = 0; s < 6; ++s)
                xf[(myrow + j) * 25 + q * 6 + s] = acc[j * 6 + s];
    }
    __syncthreads();
    if (kh == 0) {
#pragma unroll
        for (int j = 0; j < 4; ++j)
#pragma unroll
            for (int s = 0; s < 6; ++s)
                xf[(myrow + j) * 25 + q * 6 + s] += acc[j * 6 + s];
    }
    __syncthreads();
#pragma unroll
    for (int i = 0; i < 3; ++i) {
        int flat = tid + 256 * i;           // [0,768): seg, row, half
        int seg  = flat >> 8;
        int rem  = flat & 255;
        int row  = rem >> 1;
        int half = rem & 1;
        float4 v;
        v.x = xf[row * 25 + seg * 8 + half * 4 + 0] + biasl[seg * 8 + half * 4 + 0];
        v.y = xf[row * 25 + seg * 8 + half * 4 + 1] + biasl[seg * 8 + half * 4 + 1];
        v.z = xf[row * 25 + seg * 8 + half * 4 + 2] + biasl[seg * 8 + half * 4 + 2];
        v.w = xf[row * 25 + seg * 8 + half * 4 + 3] + biasl[seg * 8 + half * 4 + 3];
        *(float4*)(out + (size_t)seg * SEG + (size_t)(rowblk + row) * 8 + half * 4) = v;
    }
}

// ---------------------------------------------------------------------------
// Pure-VALU cross-lane helpers
// ---------------------------------------------------------------------------
#define DPPF(x, ctrl) __int_as_float(__builtin_amdgcn_update_dpp(              \
    0, __float_as_int(x), ctrl, 0xF, 0xF, true))
#define SWIZF(x, pat) __int_as_float(__builtin_amdgcn_ds_swizzle(              \
    __float_as_int(x), pat))
#define BPERMF(a, x)  __int_as_float(__builtin_amdgcn_ds_bpermute(             \
    a, __float_as_int(x)))

__device__ __forceinline__ float rfl(float x) {
    return __int_as_float(__builtin_amdgcn_readfirstlane(__float_as_int(x)));
}

#if __has_builtin(__builtin_amdgcn_permlane16_swap)
__device__ __forceinline__ float xor16f(float x, int lane) {
    typedef unsigned uv2 __attribute__((ext_vector_type(2)));
    uv2 r = __builtin_amdgcn_permlane16_swap(__float_as_uint(x), __float_as_uint(x), false, false);
    return __uint_as_float((lane & 16) ? r.x : r.y);
}
#else
__device__ __forceinline__ float xor16f(float x, int lane) { return SWIZF(x, 0x401F); }
#endif

#if __has_builtin(__builtin_amdgcn_permlane32_swap)
__device__ __forceinline__ float xor32f(float x, int lane) {
    typedef unsigned uv2 __attribute__((ext_vector_type(2)));
    uv2 r = __builtin_amdgcn_permlane32_swap(__float_as_uint(x), __float_as_uint(x), false, false);
    return __uint_as_float((lane & 32) ? r.x : r.y);
}
#else
__device__ __forceinline__ float xor32f(float x, int lane) {
    return BPERMF(((lane ^ 32) << 2), x);
}
#endif

// ---------------------------------------------------------------------------
// Kernel 2: 192 blocks x 128 threads (2 waves). Wave 0: Viterbi (bit-exact,
// ballot argmax, chunked backtrack). Wave 1: CRF logZ in multiplicative form
// (no exp/log on the recurrence chain) + scores. (R5-R9 version, proven.)
// ---------------------------------------------------------------------------
__global__ __launch_bounds__(128) void crf_vit(
    const float* __restrict__ logits,
    const int* __restrict__ labels,
    const int* __restrict__ lens,
    const float* __restrict__ trans_t,
    const float* __restrict__ trans_p,
    const float* __restrict__ trans_m,
    float* __restrict__ out_tags,
    float* __restrict__ partial)
{
    __shared__ float llds[TT * KK];        // 16 KB
    __shared__ unsigned bpw[TT * 2];       // 4 KB backpointers (wave-0 private)
    __shared__ unsigned fmapw[64][2];
    __shared__ unsigned char bnd[64];

    int blk = blockIdx.x;
    int h   = blk >> 6;
    int b   = blk & 63;
    int tid = threadIdx.x;
    int wid = __builtin_amdgcn_readfirstlane(tid >> 6);
    int lane = tid & 63;
    int hi = lane >> 3, lo = lane & 7;
    unsigned char* bpb = (unsigned char*)bpw;

    const float* L = logits + ((size_t)h * BATCH + b) * (TT * KK);
    const float4* Lv = (const float4*)L;
    float4* lv = (float4*)llds;
#pragma unroll
    for (int i = 0; i < 8; ++i) lv[tid + 128 * i] = Lv[tid + 128 * i];
    __syncthreads();

    const float* TR = (h == 0) ? trans_t : (h == 1) ? trans_p : trans_m;
    int len = lens[b];
    float trA = TR[lo * 8 + hi];   // even step: kp=lo -> kn=hi
    float trB = TR[hi * 8 + lo];   // odd step:  kp=hi -> kn=lo

    if (wid == 0) {
        // ================= Viterbi wave (bit-exact) =================
        float av = llds[lo];

#define VIT_EVEN(t, LT)                                                        \
    {                                                                          \
        float v0 = av + trA;                                                   \
        float ra = fmaxf(v0, DPPF(v0, 0xB1));                                  \
        float rb = fmaxf(ra, DPPF(ra, 0x4E));                                  \
        float vmax = fmaxf(rb, DPPF(rb, 0x141));                               \
        unsigned long long mk = __ballot(v0 == vmax);                          \
        int vi = __builtin_ctz(((unsigned)(mk >> (lane & 56))) & 0xffu);       \
        if (lo == 0) bpb[(t) * 8 + hi] = (unsigned char)vi;                    \
        av = vmax + (LT);                                                      \
    }
#define VIT_ODD(t, LT)                                                         \
    {                                                                          \
        float v0 = av + trB;                                                   \
        float ra = fmaxf(v0, DPPF(v0, 0x128));                                 \
        float rb = fmaxf(ra, xor16f(ra, lane));                                \
        float vmax = fmaxf(rb, xor32f(rb, lane));                              \
        unsigned long long mk = __ballot(v0 == vmax);                          \
        unsigned long long sel = (mk >> lo) & 0x0101010101010101ULL;           \
        int vi = __builtin_ctzll(sel) >> 3;                                    \
        if (hi == 0) bpb[(t) * 8 + lo] = (unsigned char)vi;                    \
        av = vmax + (LT);                                                      \
    }

        float ltA = llds[8 + hi];
        float ltB = llds[16 + lo];
        for (int t = 1; t <= 509; t += 2) {
            float ltA2 = llds[(t + 2) * 8 + hi];
            int tb = (t + 3 <= 511) ? (t + 3) : 511;
            float ltB2 = llds[tb * 8 + lo];
            VIT_EVEN(t, ltA);
            VIT_ODD(t + 1, ltB);
            ltA = ltA2; ltB = ltB2;
        }
        VIT_EVEN(511, ltA);
#undef VIT_EVEN
#undef VIT_ODD

        float ra = fmaxf(av, DPPF(av, 0x128));
        float rb = fmaxf(ra, xor16f(ra, lane));
        float vmax = fmaxf(rb, xor32f(rb, lane));
        unsigned long long mk = __ballot(av == vmax);
        int last_ = __builtin_ctzll(mk) >> 3;

        asm volatile("" ::: "memory");

        // Phase A: lane l composes bp maps for t in [8l+1, 8l+8]
        int t0 = lane * 8;
        unsigned rw[16];
#pragma unroll
        for (int j = 0; j < 8; ++j) {
            int t = t0 + 1 + j;
            if (t <= 511) { rw[2 * j] = bpw[t * 2]; rw[2 * j + 1] = bpw[t * 2 + 1]; }
            else          { rw[2 * j] = 0x03020100u; rw[2 * j + 1] = 0x07060504u; }
        }
        unsigned sv[8];
#pragma unroll
        for (int i = 0; i < 8; ++i) sv[i] = i;
#pragma unroll
        for (int j = 7; j >= 0; --j) {
            unsigned d0 = rw[2 * j], d1 = rw[2 * j + 1];
#pragma unroll
            for (int i = 0; i < 8; ++i) {
                unsigned s = sv[i];
                unsigned d = (s < 4) ? d0 : d1;
                sv[i] = (d >> (8 * (s & 3))) & 0xffu;
            }
        }
        fmapw[lane][0] = sv[0] | (sv[1] << 8) | (sv[2] << 16) | (sv[3] << 24);
        fmapw[lane][1] = sv[4] | (sv[5] << 8) | (sv[6] << 16) | (sv[7] << 24);
        asm volatile("" ::: "memory");

        if (lane == 0) {
            unsigned cur = (unsigned)last_;
            for (int l = 63; l >= 0; --l) {
                unsigned d = (cur < 4) ? fmapw[l][0] : fmapw[l][1];
                cur = (d >> (8 * (cur & 3))) & 0xffu;
                bnd[l] = (unsigned char)cur;
            }
        }
        asm volatile("" ::: "memory");

        int off = h * 8;
        float* otag = out_tags + b * (3 * TT) + h * TT;
        unsigned curr = (lane == 63) ? (unsigned)last_ : (unsigned)bnd[lane + 1];
#pragma unroll
        for (int j = 7; j >= 0; --j) {
            unsigned d = (curr < 4) ? rw[2 * j] : rw[2 * j + 1];
            curr = (d >> (8 * (curr & 3))) & 0xffu;
            otag[t0 + j] = (float)((int)curr + off);
        }
    } else {
        // ============ CRF wave: multiplicative logsumexp ============
        float EA = __expf(trA);
        float EB = __expf(trB);
        float al0 = llds[lo];
        float c0 = rfl(al0);
        float S = __expf(al0 - c0);
        float Mc = c0;
        float r2 = 0.f, r3 = 0.f;
        const float LN8 = 2.0794415416798357f;

#define LSE_EVEN(t, LT)                                                        \
    {                                                                          \
        float c = rfl(LT) + LN8;                                               \
        float F = __expf((LT) - c);                                            \
        float P = S * EA;                                                      \
        float sa = P + DPPF(P, 0xB1);                                          \
        float sb = sa + DPPF(sa, 0x4E);                                        \
        float ss = sb + DPPF(sb, 0x141);                                       \
        if ((t) < len) { S = ss * F; Mc += c; }                                \
        r2 = r3; r3 = __logf(rfl(S));                                          \
    }
#define LSE_ODD(t, LT)                                                         \
    {                                                                          \
        float c = rfl(LT) + LN8;                                               \
        float F = __expf((LT) - c);                                            \
        float P = S * EB;                                                      \
        float sa = P + DPPF(P, 0x128);                                         \
        float sb = sa + xor16f(sa, lane);                                      \
        float ss = sb + xor32f(sb, lane);                                      \
        if ((t) < len) { S = ss * F; Mc += c; }                                \
        r2 = r3; r3 = __logf(rfl(S));                                          \
    }

        float ltA = llds[8 + hi];
        float ltB = llds[16 + lo];
        for (int t = 1; t <= 509; t += 2) {
            if ((t & 3) == 1) {
                float g = r2;
                S *= __expf(-g);
                Mc += g;
            }
            float ltA2 = llds[(t + 2) * 8 + hi];
            int tb = (t + 3 <= 511) ? (t + 3) : 511;
            float ltB2 = llds[tb * 8 + lo];
            LSE_EVEN(t, ltA);
            LSE_ODD(t + 1, ltB);
            ltA = ltA2; ltB = ltB2;
        }
        LSE_EVEN(511, ltA);
#undef LSE_EVEN
#undef LSE_ODD

        float aj = Mc + __logf(S);
        float za = fmaxf(aj, DPPF(aj, 0x128));
        float zb = fmaxf(za, xor16f(za, lane));
        float zmax = fmaxf(zb, xor32f(zb, lane));
        float ze = __expf(aj - zmax);
        float zs = ze + DPPF(ze, 0x128);
        float zs2 = zs + xor16f(zs, lane);
        float zsum = zs2 + xor32f(zs2, lane);
        float logZ = zmax + __logf(zsum);

        const int* lab = labels + b * (3 * TT) + h * TT;
        int off = h * 8;
        float sc = 0.f;
#pragma unroll
        for (int j = 0; j < 8; ++j) {
            int t = lane + 64 * j;
            if (t < len) {
                int tg = lab[t] - off;
                sc += llds[t * 8 + tg];
                if (t >= 1) {
                    int tp = lab[t - 1] - off;
                    sc += TR[tp * 8 + tg];
                }
            }
        }
#pragma unroll
        for (int d = 1; d <= 32; d <<= 1) sc += __shfl_xor(sc, d);

        if (lane == 0) partial[blk] = logZ - sc;
    }
}

// ---------------------------------------------------------------------------
// Kernel 3: deterministic loss reduction (192 partials -> scalar)
// ---------------------------------------------------------------------------
__global__ __launch_bounds__(64) void loss_reduce(
    const float* __restrict__ partial, float* __restrict__ out_loss)
{
    int lane = threadIdx.x;
    float s = partial[lane] + partial[lane + 64] + partial[lane + 128];
#pragma unroll
    for (int d = 1; d <= 32; d <<= 1) s += __shfl_xor(s, d);
    if (lane == 0) *out_loss = s;
}

// ---------------------------------------------------------------------------
extern "C" void kernel_launch(void* const* d_in, const int* in_sizes, int n_in,
                              void* d_out, int out_size, void* d_ws, size_t ws_size,
                              hipStream_t stream) {
    const float* enc    = (const float*)d_in[0];
    const int*   labels = (const int*)d_in[1];
    const int*   lens   = (const int*)d_in[2];
    const float* Wt     = (const float*)d_in[3];
    const float* bt     = (const float*)d_in[4];
    const float* Wp     = (const float*)d_in[5];
    const float* bpv    = (const float*)d_in[6];
    const float* Wm     = (const float*)d_in[7];
    const float* bm     = (const float*)d_in[8];
    const float* tr_t   = (const float*)d_in[9];
    const float* tr_p   = (const float*)d_in[10];
    const float* tr_m   = (const float*)d_in[11];

    float* out = (float*)d_out;
    float* lpart = (float*)d_ws;   // 192 floats

    gemm_heads<<<256, 256, 0, stream>>>(enc, Wt, bt, Wp, bpv, Wm, bm, out);
    crf_vit<<<192, 128, 0, stream>>>(out, labels, lens, tr_t, tr_p, tr_m,
                                     out + TAGS_OFF, lpart);
    loss_reduce<<<1, 64, 0, stream>>>(lpart, out + LOSS_OFF);
}

// Round 11
// 87.923 us; speedup vs baseline: 3.0683x; 1.0019x over previous
//
#include <hip/hip_runtime.h>
#include <hip/hip_bf16.h>
#include <math.h>

#define BATCH 64
#define TT 512
#define HH 1024
#define KK 8
#define ROWS (BATCH * TT)          // 32768
#define SEG  (ROWS * KK)           // 262144 floats per logits output
#define TAGS_OFF (3 * SEG)         // 786432
#define LOSS_OFF (TAGS_OFF + BATCH * 3 * TT)  // 884736

// ---------------------------------------------------------------------------
// Kernel 1: fused 3-head GEMM. 512 blocks x 256 thr (4 waves), block = 64
// rows, wave = K-QUARTER (R11: R10's cheap per-hh DS recipe + R7's 8 waves/CU
// for cross-wave latency hiding; R10 at 1 wave/SIMD was stall-bound at ~2x its
// DS floor). Lane = (r16, q4): 4 rows x 6 outputs, acc[24]. Per hh: 1
// ds_read_b128 x + b128+b64 weights (4 distinct q-addresses, hh-XOR-swizzled)
// + 24 FMA. Per-wave PRIVATE double-buffered tiles (no main-loop barriers).
// In-block 4-way K-reduce via LDS overlay; coalesced bias-fused store.
// ---------------------------------------------------------------------------
__global__ __launch_bounds__(256, 2) void gemm_heads(
    const float* __restrict__ enc,
    const float* __restrict__ Wt, const float* __restrict__ bt,
    const float* __restrict__ Wp, const float* __restrict__ bpv,
    const float* __restrict__ Wm, const float* __restrict__ bm,
    float* __restrict__ out)
{
    __shared__ float xt[4][2][16][68];    // 34.8 KB per-wave x tiles (padded)
    __shared__ float wl[4][2][16][32];    // 16.4 KB per-wave weight tiles
    __shared__ float biasl[24];

    int tid  = threadIdx.x;
    int lane = tid & 63;
    int w    = __builtin_amdgcn_readfirstlane(tid >> 6);  // K-quarter 0..3
    int r    = lane >> 2;        // row group 0..15 (rows 4r..4r+3)
    int q    = lane & 3;         // output group 0..3 (outputs 6q..6q+5)
    int rowblk = blockIdx.x * 64;

    if (tid < 24) {
        int hd = tid >> 3, cl = tid & 7;
        biasl[tid] = (hd == 0) ? bt[cl] : (hd == 1) ? bpv[cl] : bm[cl];
    }

    const float* encw = enc + (size_t)rowblk * HH + w * 256;
    const float* Wkt = Wt + w * 2048;     // quarter base: 256 h x 8 cols
    const float* Wkp = Wp + w * 2048;
    const float* Wkm = Wm + w * 2048;

    int srow = lane >> 2;        // staging row base (adds 16*i)
    int schunk = lane & 3;       // staging h-chunk

    float acc[24];
#pragma unroll
    for (int c = 0; c < 24; ++c) acc[c] = 0.f;

    float4 sreg[4];
    float  wreg[6];

#define LOADT(it)                                                             \
    {                                                                         \
        _Pragma("unroll")                                                     \
        for (int i = 0; i < 4; ++i)                                           \
            sreg[i] = *(const float4*)(encw + (size_t)(srow + 16 * i) * HH +  \
                                       (it) * 16 + schunk * 4);               \
    }
#define WRITET(buf)                                                           \
    {                                                                         \
        _Pragma("unroll")                                                     \
        for (int i = 0; i < 4; ++i) {                                         \
            xt[w][buf][schunk * 4 + 0][srow + 16 * i] = sreg[i].x;            \
            xt[w][buf][schunk * 4 + 1][srow + 16 * i] = sreg[i].y;            \
            xt[w][buf][schunk * 4 + 2][srow + 16 * i] = sreg[i].z;            \
            xt[w][buf][schunk * 4 + 3][srow + 16 * i] = sreg[i].w;            \
        }                                                                     \
    }
#define WLOADG(it)                                                            \
    {                                                                         \
        wreg[0] = Wkt[(it) * 128 + lane]; wreg[1] = Wkt[(it) * 128 + 64 + lane]; \
        wreg[2] = Wkp[(it) * 128 + lane]; wreg[3] = Wkp[(it) * 128 + 64 + lane]; \
        wreg[4] = Wkm[(it) * 128 + lane]; wreg[5] = Wkm[(it) * 128 + 64 + lane]; \
    }
// float i of WLOADG = W[head=i>>1][h = (lane>>3)+8*(i&1)][col = lane&7]
// -> output c = 8*(i>>1)+col, q' = c/6, slot = c%6, store at hh-XOR-swizzled q
#define WWRITE(buf)                                                           \
    {                                                                         \
        int col_ = lane & 7;                                                  \
        _Pragma("unroll")                                                     \
        for (int i = 0; i < 6; ++i) {                                         \
            int hh_ = (lane >> 3) + 8 * (i & 1);                              \
            int c_  = 8 * (i >> 1) + col_;                                    \
            int q_  = (c_ * 43) >> 8;      /* c/6 for c<24 */                 \
            int s_  = c_ - 6 * q_;                                            \
            wl[w][buf][hh_][8 * (q_ ^ (hh_ & 3)) + s_] = wreg[i];             \
        }                                                                     \
    }

    LOADT(0)
    WLOADG(0)
    WRITET(0)
    WWRITE(0)

    for (int it = 0; it < 16; ++it) {
        int cb = it & 1;
        if (it < 15) {                      // issue next tile's loads early
            LOADT(it + 1)
            WLOADG(it + 1)
        }
#pragma unroll
        for (int hh = 0; hh < 16; ++hh) {
            float4 xv = *(const float4*)&xt[w][cb][hh][4 * r];
            const float* wp_ = &wl[w][cb][hh][8 * (q ^ (hh & 3))];
            float4 w0 = *(const float4*)wp_;          // weights 6q..6q+3
            float2 w1 = *(const float2*)(wp_ + 4);    // weights 6q+4..6q+5
#pragma unroll
            for (int j = 0; j < 4; ++j) {
                float xe = (j == 0) ? xv.x : (j == 1) ? xv.y : (j == 2) ? xv.z : xv.w;
                acc[j * 6 + 0] = fmaf(xe, w0.x, acc[j * 6 + 0]);
                acc[j * 6 + 1] = fmaf(xe, w0.y, acc[j * 6 + 1]);
                acc[j * 6 + 2] = fmaf(xe, w0.z, acc[j * 6 + 2]);
                acc[j * 6 + 3] = fmaf(xe, w0.w, acc[j * 6 + 3]);
                acc[j * 6 + 4] = fmaf(xe, w1.x, acc[j * 6 + 4]);
                acc[j * 6 + 5] = fmaf(xe, w1.y, acc[j * 6 + 5]);
            }
        }
        if (it < 31) {                      // write-late; per-wave private
            WRITET(cb ^ 1)
            WWRITE(cb ^ 1)
        }
    }
#undef LOADT
#undef WRITET
#undef WLOADG
#undef WWRITE

    // ---- 4-way K-quarter reduce + coalesced store via LDS overlay --------
    // overlay fin[4 slices][64][25] on xt region (25.6 KB < 34.8 KB).
    __syncthreads();
    float* xf = &xt[0][0][0][0];
    int myrow = 4 * r;
    if (w != 0) {
        float* sl = xf + w * 1600;          // slice w: [64][25]
#pragma unroll
        for (int j = 0; j < 4; ++j)
#pragma unroll
            for (int s = 0; s < 6; ++s)
                sl[(myrow + j) * 25 + q * 6 + s] = acc[j * 6 + s];
    }
    __syncthreads();
    if (w == 0) {
#pragma unroll
        for (int j = 0; j < 4; ++j)
#pragma unroll
            for (int s = 0; s < 6; ++s)
                xf[(myrow + j) * 25 + q * 6 + s] =
                    acc[j * 6 + s] + xf[1600 + (myrow + j) * 25 + q * 6 + s]
                                   + xf[3200 + (myrow + j) * 25 + q * 6 + s]
                                   + xf[4800 + (myrow + j) * 25 + q * 6 + s];
    }
    __syncthreads();
    // 64 rows x 3 segs x 2 halves = 384 float4 stores
#pragma unroll
    for (int i = 0; i < 2; ++i) {
        int flat = tid + 256 * i;
        if (flat < 384) {
            int seg  = flat >> 7;
            int rem  = flat & 127;
            int row  = rem >> 1;
            int half = rem & 1;
            float4 v;
            v.x = xf[row * 25 + seg * 8 + half * 4 + 0] + biasl[seg * 8 + half * 4 + 0];
            v.y = xf[row * 25 + seg * 8 + half * 4 + 1] + biasl[seg * 8 + half * 4 + 1];
            v.z = xf[row * 25 + seg * 8 + half * 4 + 2] + biasl[seg * 8 + half * 4 + 2];
            v.w = xf[row * 25 + seg * 8 + half * 4 + 3] + biasl[seg * 8 + half * 4 + 3];
            *(float4*)(out + (size_t)seg * SEG + (size_t)(rowblk + row) * 8 + half * 4) = v;
        }
    }
}

// ---------------------------------------------------------------------------
// Pure-VALU cross-lane helpers
// ---------------------------------------------------------------------------
#define DPPF(x, ctrl) __int_as_float(__builtin_amdgcn_update_dpp(              \
    0, __float_as_int(x), ctrl, 0xF, 0xF, true))
#define SWIZF(x, pat) __int_as_float(__builtin_amdgcn_ds_swizzle(              \
    __float_as_int(x), pat))
#define BPERMF(a, x)  __int_as_float(__builtin_amdgcn_ds_bpermute(             \
    a, __float_as_int(x)))

__device__ __forceinline__ float rfl(float x) {
    return __int_as_float(__builtin_amdgcn_readfirstlane(__float_as_int(x)));
}

#if __has_builtin(__builtin_amdgcn_permlane16_swap)
__device__ __forceinline__ float xor16f(float x, int lane) {
    typedef unsigned uv2 __attribute__((ext_vector_type(2)));
    uv2 r = __builtin_amdgcn_permlane16_swap(__float_as_uint(x), __float_as_uint(x), false, false);
    return __uint_as_float((lane & 16) ? r.x : r.y);
}
#else
__device__ __forceinline__ float xor16f(float x, int lane) { return SWIZF(x, 0x401F); }
#endif

#if __has_builtin(__builtin_amdgcn_permlane32_swap)
__device__ __forceinline__ float xor32f(float x, int lane) {
    typedef unsigned uv2 __attribute__((ext_vector_type(2)));
    uv2 r = __builtin_amdgcn_permlane32_swap(__float_as_uint(x), __float_as_uint(x), false, false);
    return __uint_as_float((lane & 32) ? r.x : r.y);
}
#else
__device__ __forceinline__ float xor32f(float x, int lane) {
    return BPERMF(((lane ^ 32) << 2), x);
}
#endif

// ---------------------------------------------------------------------------
// Kernel 2: 192 blocks x 128 threads (2 waves). Wave 0: Viterbi (bit-exact,
// ballot argmax, chunked backtrack). Wave 1: CRF logZ in multiplicative form
// (no exp/log on the recurrence chain) + scores. (R5-R10 version, proven.)
// ---------------------------------------------------------------------------
__global__ __launch_bounds__(128) void crf_vit(
    const float* __restrict__ logits,
    const int* __restrict__ labels,
    const int* __restrict__ lens,
    const float* __restrict__ trans_t,
    const float* __restrict__ trans_p,
    const float* __restrict__ trans_m,
    float* __restrict__ out_tags,
    float* __restrict__ partial)
{
    __shared__ float llds[TT * KK];        // 16 KB
    __shared__ unsigned bpw[TT * 2];       // 4 KB backpointers (wave-0 private)
    __shared__ unsigned fmapw[64][2];
    __shared__ unsigned char bnd[64];

    int blk = blockIdx.x;
    int h   = blk >> 6;
    int b   = blk & 63;
    int tid = threadIdx.x;
    int wid = __builtin_amdgcn_readfirstlane(tid >> 6);
    int lane = tid & 63;
    int hi = lane >> 3, lo = lane & 7;
    unsigned char* bpb = (unsigned char*)bpw;

    const float* L = logits + ((size_t)h * BATCH + b) * (TT * KK);
    const float4* Lv = (const float4*)L;
    float4* lv = (float4*)llds;
#pragma unroll
    for (int i = 0; i < 8; ++i) lv[tid + 128 * i] = Lv[tid + 128 * i];
    __syncthreads();

    const float* TR = (h == 0) ? trans_t : (h == 1) ? trans_p : trans_m;
    int len = lens[b];
    float trA = TR[lo * 8 + hi];   // even step: kp=lo -> kn=hi
    float trB = TR[hi * 8 + lo];   // odd step:  kp=hi -> kn=lo

    if (wid == 0) {
        // ================= Viterbi wave (bit-exact) =================
        float av = llds[lo];

#define VIT_EVEN(t, LT)                                                        \
    {                                                                          \
        float v0 = av + trA;                                                   \
        float ra = fmaxf(v0, DPPF(v0, 0xB1));                                  \
        float rb = fmaxf(ra, DPPF(ra, 0x4E));                                  \
        float vmax = fmaxf(rb, DPPF(rb, 0x141));                               \
        unsigned long long mk = __ballot(v0 == vmax);                          \
        int vi = __builtin_ctz(((unsigned)(mk >> (lane & 56))) & 0xffu);       \
        if (lo == 0) bpb[(t) * 8 + hi] = (unsigned char)vi;                    \
        av = vmax + (LT);                                                      \
    }
#define VIT_ODD(t, LT)                                                         \
    {                                                                          \
        float v0 = av + trB;                                                   \
        float ra = fmaxf(v0, DPPF(v0, 0x128));                                 \
        float rb = fmaxf(ra, xor16f(ra, lane));                                \
        float vmax = fmaxf(rb, xor32f(rb, lane));                              \
        unsigned long long mk = __ballot(v0 == vmax);                          \
        unsigned long long sel = (mk >> lo) & 0x0101010101010101ULL;           \
        int vi = __builtin_ctzll(sel) >> 3;                                    \
        if (hi == 0) bpb[(t) * 8 + lo] = (unsigned char)vi;                    \
        av = vmax + (LT);                                                      \
    }

        float ltA = llds[8 + hi];
        float ltB = llds[16 + lo];
        for (int t = 1; t <= 509; t += 2) {
            float ltA2 = llds[(t + 2) * 8 + hi];
            int tb = (t + 3 <= 511) ? (t + 3) : 511;
            float ltB2 = llds[tb * 8 + lo];
            VIT_EVEN(t, ltA);
            VIT_ODD(t + 1, ltB);
            ltA = ltA2; ltB = ltB2;
        }
        VIT_EVEN(511, ltA);
#undef VIT_EVEN
#undef VIT_ODD

        float ra = fmaxf(av, DPPF(av, 0x128));
        float rb = fmaxf(ra, xor16f(ra, lane));
        float vmax = fmaxf(rb, xor32f(rb, lane));
        unsigned long long mk = __ballot(av == vmax);
        int last_ = __builtin_ctzll(mk) >> 3;

        asm volatile("" ::: "memory");

        // Phase A: lane l composes bp maps for t in [8l+1, 8l+8]
        int t0 = lane * 8;
        unsigned rw[16];
#pragma unroll
        for (int j = 0; j < 8; ++j) {
            int t = t0 + 1 + j;
            if (t <= 511) { rw[2 * j] = bpw[t * 2]; rw[2 * j + 1] = bpw[t * 2 + 1]; }
            else          { rw[2 * j] = 0x03020100u; rw[2 * j + 1] = 0x07060504u; }
        }
        unsigned sv[8];
#pragma unroll
        for (int i = 0; i < 8; ++i) sv[i] = i;
#pragma unroll
        for (int j = 7; j >= 0; --j) {
            unsigned d0 = rw[2 * j], d1 = rw[2 * j + 1];
#pragma unroll
            for (int i = 0; i < 8; ++i) {
                unsigned s = sv[i];
                unsigned d = (s < 4) ? d0 : d1;
                sv[i] = (d >> (8 * (s & 3))) & 0xffu;
            }
        }
        fmapw[lane][0] = sv[0] | (sv[1] << 8) | (sv[2] << 16) | (sv[3] << 24);
        fmapw[lane][1] = sv[4] | (sv[5] << 8) | (sv[6] << 16) | (sv[7] << 24);
        asm volatile("" ::: "memory");

        if (lane == 0) {
            unsigned cur = (unsigned)last_;
            for (int l = 63; l >= 0; --l) {
                unsigned d = (cur < 4) ? fmapw[l][0] : fmapw[l][1];
                cur = (d >> (8 * (cur & 3))) & 0xffu;
                bnd[l] = (unsigned char)cur;
            }
        }
        asm volatile("" ::: "memory");

        int off = h * 8;
        float* otag = out_tags + b * (3 * TT) + h * TT;
        unsigned curr = (lane == 63) ? (unsigned)last_ : (unsigned)bnd[lane + 1];
#pragma unroll
        for (int j = 7; j >= 0; --j) {
            unsigned d = (curr < 4) ? rw[2 * j] : rw[2 * j + 1];
            curr = (d >> (8 * (curr & 3))) & 0xffu;
            otag[t0 + j] = (float)((int)curr + off);
        }
    } else {
        // ============ CRF wave: multiplicative logsumexp ============
        float EA = __expf(trA);
        float EB = __expf(trB);
        float al0 = llds[lo];
        float c0 = rfl(al0);
        float S = __expf(al0 - c0);
        float Mc = c0;
        float r2 = 0.f, r3 = 0.f;
        const float LN8 = 2.0794415416798357f;

#define LSE_EVEN(t, LT)                                                        \
    {                                                                          \
        float c = rfl(LT) + LN8;                                               \
        float F = __expf((LT) - c);                                            \
        float P = S * EA;                                                      \
        float sa = P + DPPF(P, 0xB1);                                          \
        float sb = sa + DPPF(sa, 0x4E);                                        \
        float ss = sb + DPPF(sb, 0x141);                                       \
        if ((t) < len) { S = ss * F; Mc += c; }                                \
        r2 = r3; r3 = __logf(rfl(S));                                          \
    }
#define LSE_ODD(t, LT)                                                         \
    {                                                                          \
        float c = rfl(LT) + LN8;                                               \
        float F = __expf((LT) - c);                                            \
        float P = S * EB;                                                      \
        float sa = P + DPPF(P, 0x128);                                         \
        float sb = sa + xor16f(sa, lane);                                      \
        float ss = sb + xor32f(sb, lane);                                      \
        if ((t) < len) { S = ss * F; Mc += c; }                                \
        r2 = r3; r3 = __logf(rfl(S));                                          \
    }

        float ltA = llds[8 + hi];
        float ltB = llds[16 + lo];
        for (int t = 1; t <= 509; t += 2) {
            if ((t & 3) == 1) {
                float g = r2;
                S *= __expf(-g);
                Mc += g;
            }
            float ltA2 = llds[(t + 2) * 8 + hi];
            int tb = (t + 3 <= 511) ? (t + 3) : 511;
            float ltB2 = llds[tb * 8 + lo];
            LSE_EVEN(t, ltA);
            LSE_ODD(t + 1, ltB);
            ltA = ltA2; ltB = ltB2;
        }
        LSE_EVEN(511, ltA);
#undef LSE_EVEN
#undef LSE_ODD

        float aj = Mc + __logf(S);
        float za = fmaxf(aj, DPPF(aj, 0x128));
        float zb = fmaxf(za, xor16f(za, lane));
        float zmax = fmaxf(zb, xor32f(zb, lane));
        float ze = __expf(aj - zmax);
        float zs = ze + DPPF(ze, 0x128);
        float zs2 = zs + xor16f(zs, lane);
        float zsum = zs2 + xor32f(zs2, lane);
        float logZ = zmax + __logf(zsum);

        const int* lab = labels + b * (3 * TT) + h * TT;
        int off = h * 8;
        float sc = 0.f;
#pragma unroll
        for (int j = 0; j < 8; ++j) {
            int t = lane + 64 * j;
            if (t < len) {
                int tg = lab[t] - off;
                sc += llds[t * 8 + tg];
                if (t >= 1) {
                    int tp = lab[t - 1] - off;
                    sc += TR[tp * 8 + tg];
                }
            }
        }
#pragma unroll
        for (int d = 1; d <= 32; d <<= 1) sc += __shfl_xor(sc, d);

        if (lane == 0) partial[blk] = logZ - sc;
    }
}

// ---------------------------------------------------------------------------
// Kernel 3: deterministic loss reduction (192 partials -> scalar)
// ---------------------------------------------------------------------------
__global__ __launch_bounds__(64) void loss_reduce(
    const float* __restrict__ partial, float* __restrict__ out_loss)
{
    int lane = threadIdx.x;
    float s = partial[lane] + partial[lane + 64] + partial[lane + 128];
#pragma unroll
    for (int d = 1; d <= 32; d <<= 1) s += __shfl_xor(s, d);
    if (lane == 0) *out_loss = s;
}

// ---------------------------------------------------------------------------
extern "C" void kernel_launch(void* const* d_in, const int* in_sizes, int n_in,
                              void* d_out, int out_size, void* d_ws, size_t ws_size,
                              hipStream_t stream) {
    const float* enc    = (const float*)d_in[0];
    const int*   labels = (const int*)d_in[1];
    const int*   lens   = (const int*)d_in[2];
    const float* Wt     = (const float*)d_in[3];
    const float* bt     = (const float*)d_in[4];
    const float* Wp     = (const float*)d_in[5];
    const float* bpv    = (const float*)d_in[6];
    const float* Wm     = (const float*)d_in[7];
    const float* bm     = (const float*)d_in[8];
    const float* tr_t   = (const float*)d_in[9];
    const float* tr_p   = (const float*)d_in[10];
    const float* tr_m   = (const float*)d_in[11];

    float* out = (float*)d_out;
    float* lpart = (float*)d_ws;   // 192 floats

    gemm_heads<<<512, 256, 0, stream>>>(enc, Wt, bt, Wp, bpv, Wm, bm, out);
    crf_vit<<<192, 128, 0, stream>>>(out, labels, lens, tr_t, tr_p, tr_m,
                                     out + TAGS_OFF, lpart);
    loss_reduce<<<1, 64, 0, stream>>>(lpart, out + LOSS_OFF);
}